// Round 1
// baseline (315.623 us; speedup 1.0000x reference)
//
#include <hip/hip_runtime.h>
#include <cstdint>

// Problem constants: B=2, L=2048, D=1024, H=16, HS=64
#define SEQ 2048
#define DMODEL 1024
#define NHEAD 16
#define HEADSZ 64

typedef __attribute__((ext_vector_type(4))) float f32x4;
typedef __attribute__((ext_vector_type(8))) short short8;
typedef __attribute__((ext_vector_type(4))) unsigned short u16x4;

#define AS1 __attribute__((address_space(1)))
#define AS3 __attribute__((address_space(3)))

__device__ __forceinline__ void gload_lds16(const void* g, void* l) {
  // async global->LDS, 16B per lane; LDS dest must be wave-uniform base (+lane*16 by HW)
  __builtin_amdgcn_global_load_lds((const AS1 void*)g, (AS3 void*)l, 16, 0, 0);
}

__device__ __forceinline__ unsigned short f2bf(float f) {
  unsigned u = __float_as_uint(f);
  u += 0x7fffu + ((u >> 16) & 1u);   // RNE
  return (unsigned short)(u >> 16);
}

// ---------------------------------------------------------------------------
// Kernel 1: fp32 -> bf16 conversion of x and concat(Wq,Wk,Wv)
// ---------------------------------------------------------------------------
__global__ __launch_bounds__(256) void convert_kernel(
    const float* __restrict__ x, const float* __restrict__ wq,
    const float* __restrict__ wk, const float* __restrict__ wv,
    unsigned short* __restrict__ xb, unsigned short* __restrict__ wb) {
  const long i = ((long)blockIdx.x * 256 + threadIdx.x) * 4;
  const float* src;
  unsigned short* dst;
  if (i < (1L << 22)) {               // x: 4M elements
    src = x + i; dst = xb + i;
  } else {
    const long j = i - (1L << 22);    // wb: 3M elements (Wq|Wk|Wv rows)
    dst = wb + j;
    if (j < (1L << 20))        src = wq + j;
    else if (j < (2L << 20))   src = wk + (j - (1L << 20));
    else                       src = wv + (j - (2L << 20));
  }
  f32x4 v = *(const f32x4*)src;
  u16x4 o;
  o.x = f2bf(v.x); o.y = f2bf(v.y); o.z = f2bf(v.z); o.w = f2bf(v.w);
  *(u16x4*)dst = o;
}

// ---------------------------------------------------------------------------
// Kernel 2: QKV projection GEMM.  out[m][n] = sum_k xb[m][k]*wb[n][k] + bias[n]
// m97 structure: 128x128 tile, BK=64, 4 waves (2x2), global_load_lds wid=16.
// Epilogue scatters Q,K as [B,H,L,64] bf16 and V transposed as [B,H,64,L].
// ---------------------------------------------------------------------------
__global__ __launch_bounds__(256) void qkv_gemm(
    const unsigned short* __restrict__ xb, const unsigned short* __restrict__ wb,
    const float* __restrict__ bq, const float* __restrict__ bk,
    const float* __restrict__ bv,
    unsigned short* __restrict__ qo, unsigned short* __restrict__ ko,
    unsigned short* __restrict__ vto) {
  __shared__ __attribute__((aligned(16))) unsigned short As[128 * 64];
  __shared__ __attribute__((aligned(16))) unsigned short Bs[128 * 64];

  const int bid = blockIdx.x;                  // nwg = 32*24 = 768 (div by 8)
  const int swz = (bid & 7) * 96 + (bid >> 3); // XCD-contiguous chunks
  const int tm = swz / 24, tn = swz % 24;
  const int m0 = tm * 128, n0 = tn * 128;
  const int t = threadIdx.x;
  const int lane = t & 63, wid = t >> 6;
  const int wr = wid >> 1, wc = wid & 1;
  const int r16 = lane & 15, g4 = lane >> 4;

  f32x4 acc[4][4] = {};

  const unsigned short* ga0 = xb + (long)(m0 + (t >> 3)) * 1024 + (t & 7) * 8;
  const unsigned short* gb0 = wb + (long)(n0 + (t >> 3)) * 1024 + (t & 7) * 8;
  char* lA = (char*)As + wid * 1024;  // wave-uniform LDS bases
  char* lB = (char*)Bs + wid * 1024;

  for (int ks = 0; ks < 16; ++ks) {
    const unsigned short* ga = ga0 + ks * 64;
    const unsigned short* gb = gb0 + ks * 64;
#pragma unroll
    for (int r = 0; r < 4; ++r) {
      gload_lds16(ga + r * 32 * 1024, lA + r * 4096);
      gload_lds16(gb + r * 32 * 1024, lB + r * 4096);
    }
    __syncthreads();   // drains vmcnt before barrier (compiler-inserted)
#pragma unroll
    for (int kk = 0; kk < 2; ++kk) {
      short8 af[4], bf[4];
#pragma unroll
      for (int mi = 0; mi < 4; ++mi)
        af[mi] = *(const short8*)((const char*)As +
                 (wr * 64 + mi * 16 + r16) * 128 + kk * 64 + g4 * 16);
#pragma unroll
      for (int ni = 0; ni < 4; ++ni)
        bf[ni] = *(const short8*)((const char*)Bs +
                 (wc * 64 + ni * 16 + r16) * 128 + kk * 64 + g4 * 16);
#pragma unroll
      for (int mi = 0; mi < 4; ++mi)
#pragma unroll
        for (int ni = 0; ni < 4; ++ni)
          acc[mi][ni] = __builtin_amdgcn_mfma_f32_16x16x32_bf16(
              af[mi], bf[ni], acc[mi][ni], 0, 0, 0);
    }
    __syncthreads();
  }

  // Epilogue: bias add, bf16 convert, head-layout scatter.
  const int tsel = n0 >> 10;  // block-uniform: 0=Q 1=K 2=V (1024%128==0)
  const float* bias = tsel == 0 ? bq : (tsel == 1 ? bk : bv);
  unsigned short* dst01 = tsel == 0 ? qo : ko;
#pragma unroll
  for (int ni = 0; ni < 4; ++ni) {
    const int n = n0 + wc * 64 + ni * 16 + r16;
    const int nd = n & 1023;
    const float bval = bias[nd];
    const int h = nd >> 6, hs = nd & 63;
#pragma unroll
    for (int mi = 0; mi < 4; ++mi) {
#pragma unroll
      for (int i = 0; i < 4; ++i) {
        const int m = m0 + wr * 64 + mi * 16 + g4 * 4 + i;  // C/D: row=(l>>4)*4+i
        const int bb = m >> 11, lpos = m & 2047;
        const unsigned short o = f2bf(acc[mi][ni][i] + bval);
        if (tsel < 2)
          dst01[(((long)(bb * NHEAD + h) * SEQ + lpos) << 6) + hs] = o;
        else  // V stored transposed: [B,H,HS,L]
          vto[((((long)(bb * NHEAD + h)) << 6) + hs) * SEQ + lpos] = o;
      }
    }
  }
}

// ---------------------------------------------------------------------------
// Kernel 3: flash attention. 1 block = (b,h, 64-row q-tile); 4 waves x 16 rows.
// KV tile = 64. Online softmax with 16-lane shfl_xor row reductions.
// ---------------------------------------------------------------------------
__global__ __launch_bounds__(256) void attn_kernel(
    const unsigned short* __restrict__ qb, const unsigned short* __restrict__ kb,
    const unsigned short* __restrict__ vtb, const float* __restrict__ mask,
    float* __restrict__ out) {
  __shared__ __attribute__((aligned(16))) unsigned short Qs[64 * 64];
  __shared__ __attribute__((aligned(16))) unsigned short Ks[64 * 64];
  __shared__ __attribute__((aligned(16))) unsigned short Vs[64 * 64];  // [hs][k]
  __shared__ __attribute__((aligned(16))) unsigned short Ps[4][16 * 64];

  const int bid = blockIdx.x;                    // nwg = 1024
  const int swz = (bid & 7) * 128 + (bid >> 3);  // 16 heads of one (b,qt) -> same XCD
  const int h = swz & 15, rest = swz >> 4;
  const int qt = rest & 31, b = rest >> 5;
  const int bh = b * NHEAD + h;

  const unsigned short* qg = qb + (long)bh * SEQ * 64 + qt * 64 * 64;
  const unsigned short* kg = kb + (long)bh * SEQ * 64;
  const unsigned short* vg = vtb + (long)bh * 64 * SEQ;
  const float* mg = mask + (long)b * SEQ * SEQ + (long)(qt * 64) * SEQ;

  const int t = threadIdx.x;
  const int lane = t & 63, w = t >> 6;
  const int r16 = lane & 15, g4 = lane >> 4;

  char* lQ = (char*)Qs + w * 1024;
  char* lK = (char*)Ks + w * 1024;
  char* lV = (char*)Vs + w * 1024;

#pragma unroll
  for (int r = 0; r < 2; ++r) {
    gload_lds16(qg + (r * 256 + t) * 8, lQ + r * 4096);
    gload_lds16(kg + (r * 256 + t) * 8, lK + r * 4096);
    gload_lds16(vg + (long)((t >> 3) + r * 32) * SEQ + (t & 7) * 8, lV + r * 4096);
  }
  __syncthreads();

  short8 qf[2];
#pragma unroll
  for (int kk = 0; kk < 2; ++kk)
    qf[kk] = *(const short8*)((const char*)Qs +
              (w * 16 + r16) * 128 + kk * 64 + g4 * 16);

  float m_st[4], l_st[4];
  f32x4 o_acc[4] = {};
#pragma unroll
  for (int i = 0; i < 4; ++i) { m_st[i] = -1e30f; l_st[i] = 0.f; }

  for (int kt = 0; kt < 32; ++kt) {
    // S = Q*K^T for this wave's 16 q-rows x 64 k-cols
    f32x4 s[4];
#pragma unroll
    for (int nf = 0; nf < 4; ++nf) {
      f32x4 z = {};
#pragma unroll
      for (int kk = 0; kk < 2; ++kk) {
        short8 kf = *(const short8*)((const char*)Ks +
                    (nf * 16 + r16) * 128 + kk * 64 + g4 * 16);
        z = __builtin_amdgcn_mfma_f32_16x16x32_bf16(qf[kk], kf, z, 0, 0, 0);
      }
      s[nf] = z;
    }
    // scale (1/sqrt(64)) + mask
#pragma unroll
    for (int nf = 0; nf < 4; ++nf)
#pragma unroll
      for (int i = 0; i < 4; ++i) {
        const float mv = mg[(long)(w * 16 + g4 * 4 + i) * SEQ +
                            kt * 64 + nf * 16 + r16];
        s[nf][i] = s[nf][i] * 0.125f + mv;
      }
    // per-row max over 64 cols: local over nf, then 16-lane butterfly
    float pm[4];
#pragma unroll
    for (int i = 0; i < 4; ++i)
      pm[i] = fmaxf(fmaxf(s[0][i], s[1][i]), fmaxf(s[2][i], s[3][i]));
#pragma unroll
    for (int x = 1; x <= 8; x <<= 1)
#pragma unroll
      for (int i = 0; i < 4; ++i)
        pm[i] = fmaxf(pm[i], __shfl_xor(pm[i], x, 64));
    float alpha[4], rs[4];
#pragma unroll
    for (int i = 0; i < 4; ++i) {
      const float mn = fmaxf(m_st[i], pm[i]);
      alpha[i] = __expf(m_st[i] - mn);
      m_st[i] = mn;
      rs[i] = 0.f;
    }
    // P = exp(s - m); write bf16 to per-wave LDS for re-fragmenting
#pragma unroll
    for (int nf = 0; nf < 4; ++nf)
#pragma unroll
      for (int i = 0; i < 4; ++i) {
        const float p = __expf(s[nf][i] - m_st[i]);
        rs[i] += p;
        Ps[w][(g4 * 4 + i) * 64 + nf * 16 + r16] = f2bf(p);
      }
#pragma unroll
    for (int x = 1; x <= 8; x <<= 1)
#pragma unroll
      for (int i = 0; i < 4; ++i)
        rs[i] += __shfl_xor(rs[i], x, 64);
#pragma unroll
    for (int i = 0; i < 4; ++i)
      l_st[i] = l_st[i] * alpha[i] + rs[i];
#pragma unroll
    for (int nd = 0; nd < 4; ++nd)
#pragma unroll
      for (int i = 0; i < 4; ++i)
        o_acc[nd][i] *= alpha[i];
    // wave-internal: ensure P stores landed before cross-lane LDS reads
    asm volatile("s_waitcnt lgkmcnt(0)" ::: "memory");
    short8 pa[2];
#pragma unroll
    for (int kk = 0; kk < 2; ++kk)
      pa[kk] = *(const short8*)((const char*)Ps[w] + r16 * 128 + kk * 64 + g4 * 16);
#pragma unroll
    for (int nd = 0; nd < 4; ++nd) {
      f32x4 z = o_acc[nd];
#pragma unroll
      for (int kk = 0; kk < 2; ++kk) {
        short8 vf = *(const short8*)((const char*)Vs +
                    (nd * 16 + r16) * 128 + kk * 64 + g4 * 16);
        z = __builtin_amdgcn_mfma_f32_16x16x32_bf16(pa[kk], vf, z, 0, 0, 0);
      }
      o_acc[nd] = z;
    }
    __syncthreads();
    if (kt < 31) {
#pragma unroll
      for (int r = 0; r < 2; ++r) {
        gload_lds16(kg + (kt + 1) * 4096 + (r * 256 + t) * 8, lK + r * 4096);
        gload_lds16(vg + (long)((t >> 3) + r * 32) * SEQ + (kt + 1) * 64 + (t & 7) * 8,
                    lV + r * 4096);
      }
      __syncthreads();
    }
  }

  // out[b, qrow, h*64 + d] fp32
  float* ob = out + (long)b * SEQ * DMODEL + (long)(qt * 64) * DMODEL + h * 64;
#pragma unroll
  for (int nd = 0; nd < 4; ++nd)
#pragma unroll
    for (int i = 0; i < 4; ++i) {
      const int qrow = w * 16 + g4 * 4 + i;
      ob[(long)qrow * DMODEL + nd * 16 + r16] = o_acc[nd][i] / l_st[i];
    }
}

// ---------------------------------------------------------------------------
extern "C" void kernel_launch(void* const* d_in, const int* in_sizes, int n_in,
                              void* d_out, int out_size, void* d_ws, size_t ws_size,
                              hipStream_t stream) {
  const float* x    = (const float*)d_in[0];
  const float* mask = (const float*)d_in[1];
  const float* Wq   = (const float*)d_in[2];
  const float* bq   = (const float*)d_in[3];
  const float* Wk   = (const float*)d_in[4];
  const float* bk   = (const float*)d_in[5];
  const float* Wv   = (const float*)d_in[6];
  const float* bv   = (const float*)d_in[7];
  float* out = (float*)d_out;

  char* ws = (char*)d_ws;
  unsigned short* xb  = (unsigned short*)(ws);                     // 8 MB
  unsigned short* wb  = (unsigned short*)(ws + (8L << 20));        // 6 MB
  unsigned short* qo  = (unsigned short*)(ws + (14L << 20));       // 8 MB
  unsigned short* ko  = (unsigned short*)(ws + (22L << 20));       // 8 MB
  unsigned short* vto = (unsigned short*)(ws + (30L << 20));       // 8 MB  (38 MB total)

  convert_kernel<<<7168, 256, 0, stream>>>(x, Wq, Wk, Wv, xb, wb);
  qkv_gemm<<<768, 256, 0, stream>>>(xb, wb, bq, bk, bv, qo, ko, vto);
  attn_kernel<<<1024, 256, 0, stream>>>(qo, ko, vto, mask, out);
}

// Round 3
// 268.335 us; speedup vs baseline: 1.1762x; 1.1762x over previous
//
#include <hip/hip_runtime.h>
#include <cstdint>

// Problem constants: B=2, L=2048, D=1024, H=16, HS=64
#define SEQ 2048
#define DMODEL 1024
#define NHEAD 16
#define HEADSZ 64

typedef __attribute__((ext_vector_type(4))) float f32x4;
typedef __attribute__((ext_vector_type(8))) short short8;
typedef __attribute__((ext_vector_type(4))) unsigned short u16x4;

#define AS1 __attribute__((address_space(1)))
#define AS3 __attribute__((address_space(3)))

__device__ __forceinline__ void gload_lds16(const void* g, void* l) {
  // async global->LDS, 16B per lane; LDS dest is wave-uniform base (+lane*16 by HW)
  __builtin_amdgcn_global_load_lds((const AS1 void*)g, (AS3 void*)l, 16, 0, 0);
}

__device__ __forceinline__ unsigned short f2bf(float f) {
  unsigned u = __float_as_uint(f);
  u += 0x7fffu + ((u >> 16) & 1u);   // RNE
  return (unsigned short)(u >> 16);
}

// ---------------------------------------------------------------------------
// Kernel 1: fp32 -> bf16 conversion of x and concat(Wq,Wk,Wv)
// ---------------------------------------------------------------------------
__global__ __launch_bounds__(256) void convert_kernel(
    const float* __restrict__ x, const float* __restrict__ wq,
    const float* __restrict__ wk, const float* __restrict__ wv,
    unsigned short* __restrict__ xb, unsigned short* __restrict__ wb) {
  const long i = ((long)blockIdx.x * 256 + threadIdx.x) * 4;
  const float* src;
  unsigned short* dst;
  if (i < (1L << 22)) {               // x: 4M elements
    src = x + i; dst = xb + i;
  } else {
    const long j = i - (1L << 22);    // wb: 3M elements (Wq|Wk|Wv rows)
    dst = wb + j;
    if (j < (1L << 20))        src = wq + j;
    else if (j < (2L << 20))   src = wk + (j - (1L << 20));
    else                       src = wv + (j - (2L << 20));
  }
  f32x4 v = *(const f32x4*)src;
  u16x4 o;
  o.x = f2bf(v.x); o.y = f2bf(v.y); o.z = f2bf(v.z); o.w = f2bf(v.w);
  *(u16x4*)dst = o;
}

// ---------------------------------------------------------------------------
// Kernel 2: QKV projection GEMM.  out[m][n] = sum_k xb[m][k]*wb[n][k] + bias[n]
// 128x128 tile, BK=64, 4 waves (2x2), global_load_lds wid=16.
// Q/K tiles: MFMA operands SWAPPED (D rows = n) so the reg-contiguous index is
// the head-dim -> u16x4 LDS-transpose writes; stores are coalesced short8 rows.
// V tile: unswapped; LDS transpose to V^T [B,H,64,L].
// All epilogues swizzle LDS with ^((row&7)<<4) and store with lpos = m&2047.
// ---------------------------------------------------------------------------
__global__ __launch_bounds__(256) void qkv_gemm(
    const unsigned short* __restrict__ xb, const unsigned short* __restrict__ wb,
    const float* __restrict__ bq, const float* __restrict__ bk,
    const float* __restrict__ bv,
    unsigned short* __restrict__ qo, unsigned short* __restrict__ ko,
    unsigned short* __restrict__ vto) {
  __shared__ __attribute__((aligned(16))) unsigned short Sh[2][128 * 64]; // 32KB
  unsigned short* As = &Sh[0][0];
  unsigned short* Bs = &Sh[1][0];

  const int bid = blockIdx.x;                  // nwg = 32*24 = 768 (div by 8)
  const int swz = (bid & 7) * 96 + (bid >> 3); // XCD-contiguous chunks
  const int tm = swz / 24, tn = swz % 24;
  const int m0 = tm * 128, n0 = tn * 128;
  const int tsel = n0 >> 10;                   // block-uniform: 0=Q 1=K 2=V
  const int t = threadIdx.x;
  const int lane = t & 63, wid = t >> 6;
  const int wr = wid >> 1, wc = wid & 1;
  const int r16 = lane & 15, g4 = lane >> 4;

  f32x4 acc[4][4] = {};

  const unsigned short* ga0 = xb + (long)(m0 + (t >> 3)) * 1024 + (t & 7) * 8;
  const unsigned short* gb0 = wb + (long)(n0 + (t >> 3)) * 1024 + (t & 7) * 8;
  char* lA = (char*)As + wid * 1024;  // wave-uniform LDS bases
  char* lB = (char*)Bs + wid * 1024;

  for (int ks = 0; ks < 16; ++ks) {
    const unsigned short* ga = ga0 + ks * 64;
    const unsigned short* gb = gb0 + ks * 64;
#pragma unroll
    for (int r = 0; r < 4; ++r) {
      gload_lds16(ga + r * 32 * 1024, lA + r * 4096);
      gload_lds16(gb + r * 32 * 1024, lB + r * 4096);
    }
    __syncthreads();
#pragma unroll
    for (int kk = 0; kk < 2; ++kk) {
      short8 af[4], bf[4];
#pragma unroll
      for (int mi = 0; mi < 4; ++mi)
        af[mi] = *(const short8*)((const char*)As +
                 (wr * 64 + mi * 16 + r16) * 128 + kk * 64 + g4 * 16);
#pragma unroll
      for (int ni = 0; ni < 4; ++ni)
        bf[ni] = *(const short8*)((const char*)Bs +
                 (wc * 64 + ni * 16 + r16) * 128 + kk * 64 + g4 * 16);
      if (tsel < 2) {
        // swapped: D[row=n][col=m]
#pragma unroll
        for (int mi = 0; mi < 4; ++mi)
#pragma unroll
          for (int ni = 0; ni < 4; ++ni)
            acc[mi][ni] = __builtin_amdgcn_mfma_f32_16x16x32_bf16(
                bf[ni], af[mi], acc[mi][ni], 0, 0, 0);
      } else {
        // normal: D[row=m][col=n]
#pragma unroll
        for (int mi = 0; mi < 4; ++mi)
#pragma unroll
          for (int ni = 0; ni < 4; ++ni)
            acc[mi][ni] = __builtin_amdgcn_mfma_f32_16x16x32_bf16(
                af[mi], bf[ni], acc[mi][ni], 0, 0, 0);
      }
    }
    __syncthreads();
  }

  const int bb = m0 >> 11;        // batch (block-uniform, 128 | 2048)
  const int lbase = m0 & 2047;    // seq position base within batch
  const int h0n = n0 & 1023;      // n base within the 1024-wide projection
  unsigned short* T = As;         // 32KB transpose buffer (spans Sh[0..1])

  if (tsel < 2) {
    // acc[mi][ni][i]: n = wc*64+ni*16+g4*4+i, m = wr*64+mi*16+r16
    const float* bias = tsel == 0 ? bq : bk;
    unsigned short* dst01 = tsel == 0 ? qo : ko;
#pragma unroll
    for (int ni = 0; ni < 4; ++ni) {
      const int nlb = wc * 64 + ni * 16 + g4 * 4;
      const f32x4 b4 = *(const f32x4*)(bias + h0n + nlb);
#pragma unroll
      for (int mi = 0; mi < 4; ++mi) {
        const int ml = wr * 64 + mi * 16 + r16;
        u16x4 pk;
#pragma unroll
        for (int i = 0; i < 4; ++i) pk[i] = f2bf(acc[mi][ni][i] + b4[i]);
        int byteoff = ml * 256 + nlb * 2;   // T[m][n], 8B write (n-contig)
        byteoff ^= (ml & 7) << 4;
        *(u16x4*)((char*)T + byteoff) = pk;
      }
    }
    __syncthreads();
#pragma unroll
    for (int p = 0; p < 8; ++p) {
      const int ml = p * 16 + (t >> 4);
      int byteoff = ml * 256 + ((t & 15) << 4);
      byteoff ^= (ml & 7) << 4;
      short8 row = *(const short8*)((const char*)T + byteoff);
      const int nd = h0n + (t & 15) * 8;    // 8 consecutive n (one head)
      const int h = nd >> 6, hs = nd & 63;
      *(short8*)(dst01 + ((long)(bb * NHEAD + h) * SEQ + lbase + ml) * 64 + hs) = row;
    }
  } else {
    // acc[mi][ni][i]: m = wr*64+mi*16+g4*4+i, n = wc*64+ni*16+r16
    // V^T wants T[n][m] with m-contig reads.
#pragma unroll
    for (int ni = 0; ni < 4; ++ni) {
      const int nl = wc * 64 + ni * 16 + r16;
      const float bval = bv[h0n + nl];
#pragma unroll
      for (int mi = 0; mi < 4; ++mi) {
        const int mlb = wr * 64 + mi * 16 + g4 * 4;
        u16x4 pk;
#pragma unroll
        for (int i = 0; i < 4; ++i) pk[i] = f2bf(acc[mi][ni][i] + bval);
        int byteoff = nl * 256 + mlb * 2;   // T[n][m], 8B write (m-contig)
        byteoff ^= (nl & 7) << 4;
        *(u16x4*)((char*)T + byteoff) = pk;
      }
    }
    __syncthreads();
#pragma unroll
    for (int p = 0; p < 8; ++p) {
      const int nl = p * 16 + (t >> 4);
      int byteoff = nl * 256 + ((t & 15) << 4);
      byteoff ^= (nl & 7) << 4;
      short8 row = *(const short8*)((const char*)T + byteoff);
      const int nd = h0n + nl;
      const int h = nd >> 6, hs = nd & 63;
      *(short8*)(vto + ((((long)(bb * NHEAD + h)) << 6) + hs) * SEQ + lbase +
                 (t & 15) * 8) = row;      // FIX: lbase (= m0 & 2047), not m0
    }
  }
}

// ---------------------------------------------------------------------------
// Kernel 3: flash attention. 1 block = (b,h, 64-row q-tile); 4 waves x 16 rows.
// KV tile = 64, double-buffered LDS, XOR-swizzled K/V/P tiles, one barrier/tile.
// ---------------------------------------------------------------------------
__global__ __launch_bounds__(256, 4) void attn_kernel(
    const unsigned short* __restrict__ qb, const unsigned short* __restrict__ kb,
    const unsigned short* __restrict__ vtb, const float* __restrict__ mask,
    float* __restrict__ out) {
  __shared__ __attribute__((aligned(16))) unsigned short Qs[64 * 64];      // 8KB; reused as P
  __shared__ __attribute__((aligned(16))) unsigned short Ks[2][64 * 64];   // 16KB dbuf
  __shared__ __attribute__((aligned(16))) unsigned short Vs[2][64 * 64];   // 16KB dbuf [hs][k]

  const int bid = blockIdx.x;                    // nwg = 1024
  const int swz = (bid & 7) * 128 + (bid >> 3);  // 16 heads of one (b,qt) -> same XCD
  const int h = swz & 15, rest = swz >> 4;
  const int qt = rest & 31, b = rest >> 5;
  const int bh = b * NHEAD + h;

  const unsigned short* qg = qb + (long)bh * SEQ * 64 + qt * 64 * 64;
  const unsigned short* kg = kb + (long)bh * SEQ * 64;
  const unsigned short* vg = vtb + (long)bh * 64 * SEQ;
  const float* mg = mask + (long)b * SEQ * SEQ + (long)(qt * 64) * SEQ;

  const int t = threadIdx.x;
  const int lane = t & 63, w = t >> 6;
  const int r16 = lane & 15, g4 = lane >> 4;
  const int rowa = t >> 3;                        // staged row within half-tile
  const int csel = ((t & 7) ^ (rowa & 7)) * 8;    // pre-swizzled k-offset (elements)
  const int swzr = (r16 & 7);                     // read-side row swizzle key

  // stage K/V tile `ktile` into buffer `buf`: swizzled global source, linear LDS
  auto stageKV = [&](int ktile, int buf) {
#pragma unroll
    for (int r = 0; r < 2; ++r) {
      gload_lds16(kg + (long)(ktile * 64 + r * 32 + rowa) * 64 + csel,
                  (char*)Ks + buf * 8192 + r * 4096 + w * 1024);
      gload_lds16(vg + (long)(r * 32 + rowa) * SEQ + ktile * 64 + csel,
                  (char*)Vs + buf * 8192 + r * 4096 + w * 1024);
    }
  };

  // prologue: Q (linear) + K0/V0
#pragma unroll
  for (int r = 0; r < 2; ++r)
    gload_lds16(qg + (r * 256 + t) * 8, (char*)Qs + r * 4096 + w * 1024);
  stageKV(0, 0);
  __syncthreads();

  short8 qf[2];
#pragma unroll
  for (int kk = 0; kk < 2; ++kk)
    qf[kk] = *(const short8*)((const char*)Qs +
              (w * 16 + r16) * 128 + kk * 64 + g4 * 16);
  // qf is in registers; wave w's Qs region (rows w*16..w*16+15) becomes its P buffer
  char* Pw = (char*)Qs + w * 2048;   // [16 q][64 k] bf16, swizzled

  float m_st[4], l_st[4];
  f32x4 o_acc[4] = {};
#pragma unroll
  for (int i = 0; i < 4; ++i) { m_st[i] = -1e30f; l_st[i] = 0.f; }

  int cur = 0;
  for (int kt = 0; kt < 32; ++kt) {
    if (kt < 31) stageKV(kt + 1, cur ^ 1);   // prefetch flies under compute

    const char* Kb = (const char*)Ks + cur * 8192;
    const char* Vb = (const char*)Vs + cur * 8192;

    float mv[4][4];
#pragma unroll
    for (int nf = 0; nf < 4; ++nf)
#pragma unroll
      for (int i = 0; i < 4; ++i)
        mv[nf][i] = mg[(long)(w * 16 + g4 * 4 + i) * SEQ +
                       kt * 64 + nf * 16 + r16];

    // S = Q*K^T  (16 q-rows x 64 k-cols per wave)
    f32x4 s[4];
#pragma unroll
    for (int nf = 0; nf < 4; ++nf) {
      f32x4 z = {};
#pragma unroll
      for (int kk = 0; kk < 2; ++kk) {
        short8 kf = *(const short8*)(Kb + (nf * 16 + r16) * 128 +
                     (((kk * 4 + g4) ^ swzr) << 4));
        z = __builtin_amdgcn_mfma_f32_16x16x32_bf16(qf[kk], kf, z, 0, 0, 0);
      }
      s[nf] = z;
    }
#pragma unroll
    for (int nf = 0; nf < 4; ++nf)
#pragma unroll
      for (int i = 0; i < 4; ++i)
        s[nf][i] = s[nf][i] * 0.125f + mv[nf][i];

    float pm[4];
#pragma unroll
    for (int i = 0; i < 4; ++i)
      pm[i] = fmaxf(fmaxf(s[0][i], s[1][i]), fmaxf(s[2][i], s[3][i]));
#pragma unroll
    for (int x = 1; x <= 8; x <<= 1)
#pragma unroll
      for (int i = 0; i < 4; ++i)
        pm[i] = fmaxf(pm[i], __shfl_xor(pm[i], x, 64));
    float alpha[4], rs[4];
#pragma unroll
    for (int i = 0; i < 4; ++i) {
      const float mn = fmaxf(m_st[i], pm[i]);
      alpha[i] = __expf(m_st[i] - mn);
      m_st[i] = mn;
      rs[i] = 0.f;
    }
#pragma unroll
    for (int nf = 0; nf < 4; ++nf)
#pragma unroll
      for (int i = 0; i < 4; ++i) {
        const float p = __expf(s[nf][i] - m_st[i]);
        rs[i] += p;
        const int q = g4 * 4 + i;
        int byteoff = q * 128 + (nf * 16 + r16) * 2;
        byteoff ^= (q & 7) << 4;
        *(unsigned short*)(Pw + byteoff) = f2bf(p);
      }
#pragma unroll
    for (int x = 1; x <= 8; x <<= 1)
#pragma unroll
      for (int i = 0; i < 4; ++i)
        rs[i] += __shfl_xor(rs[i], x, 64);
#pragma unroll
    for (int i = 0; i < 4; ++i)
      l_st[i] = l_st[i] * alpha[i] + rs[i];
#pragma unroll
    for (int nd = 0; nd < 4; ++nd)
#pragma unroll
      for (int i = 0; i < 4; ++i)
        o_acc[nd][i] *= alpha[i];

    // wave-local P write->read ordering (same-wave DS is in-order; waitcnt for compiler)
    asm volatile("s_waitcnt lgkmcnt(0)" ::: "memory");
    short8 pa[2];
#pragma unroll
    for (int kk = 0; kk < 2; ++kk)
      pa[kk] = *(const short8*)(Pw + r16 * 128 + (((kk * 4 + g4) ^ swzr) << 4));
#pragma unroll
    for (int nd = 0; nd < 4; ++nd) {
      f32x4 z = o_acc[nd];
#pragma unroll
      for (int kk = 0; kk < 2; ++kk) {
        short8 vf = *(const short8*)(Vb + (nd * 16 + r16) * 128 +
                     (((kk * 4 + g4) ^ swzr) << 4));
        z = __builtin_amdgcn_mfma_f32_16x16x32_bf16(pa[kk], vf, z, 0, 0, 0);
      }
      o_acc[nd] = z;
    }

    __syncthreads();   // drains prefetch vmcnt + publishes buffers; 1 barrier/tile
    cur ^= 1;
  }

  float* ob = out + (long)b * SEQ * DMODEL + (long)(qt * 64) * DMODEL + h * 64;
#pragma unroll
  for (int nd = 0; nd < 4; ++nd)
#pragma unroll
    for (int i = 0; i < 4; ++i) {
      const int qrow = w * 16 + g4 * 4 + i;
      ob[(long)qrow * DMODEL + nd * 16 + r16] = o_acc[nd][i] / l_st[i];
    }
}

// ---------------------------------------------------------------------------
extern "C" void kernel_launch(void* const* d_in, const int* in_sizes, int n_in,
                              void* d_out, int out_size, void* d_ws, size_t ws_size,
                              hipStream_t stream) {
  const float* x    = (const float*)d_in[0];
  const float* mask = (const float*)d_in[1];
  const float* Wq   = (const float*)d_in[2];
  const float* bq   = (const float*)d_in[3];
  const float* Wk   = (const float*)d_in[4];
  const float* bk   = (const float*)d_in[5];
  const float* Wv   = (const float*)d_in[6];
  const float* bv   = (const float*)d_in[7];
  float* out = (float*)d_out;

  char* ws = (char*)d_ws;
  unsigned short* xb  = (unsigned short*)(ws);                     // 8 MB
  unsigned short* wb  = (unsigned short*)(ws + (8L << 20));        // 6 MB
  unsigned short* qo  = (unsigned short*)(ws + (14L << 20));       // 8 MB
  unsigned short* ko  = (unsigned short*)(ws + (22L << 20));       // 8 MB
  unsigned short* vto = (unsigned short*)(ws + (30L << 20));       // 8 MB  (38 MB total)

  convert_kernel<<<7168, 256, 0, stream>>>(x, Wq, Wk, Wv, xb, wb);
  qkv_gemm<<<768, 256, 0, stream>>>(xb, wb, bq, bk, bv, qo, ko, vto);
  attn_kernel<<<1024, 256, 0, stream>>>(qo, ko, vto, mask, out);
}